// Round 10
// baseline (369.759 us; speedup 1.0000x reference)
//
#include <hip/hip_runtime.h>

// ---------------------------------------------------------------------------
// SelfInteraction: 2 layers of (tensor-square -> invariant-gated MLP -> equiv
// linear) + residual + eq-layernorm, N=16384 rows, C=128, all fp32 I/O.
// fp16 hi/lo split-precision MFMA GEMMs (22-bit effective mantissa).
// Revision r10 = r9 (depth-2 K-loop pipeline) + race hardening:
//   * r9's raw s_barrier is NOT a compiler memory fence -> LLVM could hoist
//     the cross-wave LDS fragment reads above it (rule-#18 class hazard).
//     Fix: ONE sched_barrier(0) after each s_barrier (pins ds_reads/MFMAs
//     below), one before the counted s_waitcnt (keeps prior work above).
//     Not the per-instruction pinning that regressed in m141.
//   * Design unchanged: 3 x 24KB LDS buffers, counted s_waitcnt vmcnt(6),
//     chunk c's loads issued 2 phases (~1400 cyc) before use; fused 3-pass
//     chunks (24 MFMA + 12 ds_read_b128 per wave per barrier); merged
//     epilogue phases; [col][2K] weights; XCD remap; both-sides swizzles.
// ---------------------------------------------------------------------------

typedef _Float16 half8 __attribute__((ext_vector_type(8)));
typedef float floatx4 __attribute__((ext_vector_type(4)));

static inline int cdiv_h(int a, int b){ return (a + b - 1) / b; }

// ---------------------------- device helpers -------------------------------

__device__ __forceinline__ void stage16(const char* gaddr, char* lds_base){
  // dest = wave-uniform base + lane*16 (measured semantics, learn_hip m104/m108)
  __builtin_amdgcn_global_load_lds((const __attribute__((address_space(1))) unsigned int*)gaddr,
                                   (__attribute__((address_space(3))) unsigned int*)lds_base,
                                   16, 0, 0);
}

__device__ __forceinline__ float wave_sum64(float x){
  #pragma unroll
  for (int m = 32; m; m >>= 1) x += __shfl_xor(x, m, 64);
  return x;
}

__device__ __forceinline__ void split_store(_Float16* p0, _Float16* p1, float v){
  _Float16 hi = (_Float16)v;
  *p0 = hi;
  *p1 = (_Float16)(v - (float)hi);
}

// pack (hi,lo) split of v into one uint (hi in low 16 bits)
__device__ __forceinline__ unsigned int pack_split(float v){
  union { _Float16 h[2]; unsigned int u; } pk;
  _Float16 hi = (_Float16)v;
  pk.h[0] = hi;
  pk.h[1] = (_Float16)(v - (float)hi);
  return pk.u;
}

// 4 packed (hi,lo) uints -> (hi0..3, lo0..3) as two uint2
__device__ __forceinline__ void unzip16(uint4 p, uint2& hi, uint2& lo){
  hi.x = (p.x & 0xffffu) | (p.y << 16);
  hi.y = (p.z & 0xffffu) | (p.w << 16);
  lo.x = (p.x >> 16) | (p.y & 0xffff0000u);
  lo.y = (p.z >> 16) | (p.w & 0xffff0000u);
}

// XCD-grouped remap: with round-robin dispatch (block i -> XCD i&7), all nx
// col-panel blocks of row panel y get the same (i&7) -> same XCD L2.
// Bijective for ny%8==0; identity fallback otherwise (correctness-safe).
__device__ __forceinline__ void remap_xcd(int id, int nx, int ny, int& x, int& y){
  if (ny & 7){ x = id % nx; y = id / nx; return; }
  int xcd = id & 7, q = id >> 3, t = q / nx;
  x = q - t*nx; y = xcd + (t << 3);
}

// ---------------------------- weight prep ----------------------------------
// All 8 weight-prep jobs in one launch. w row-major (K, ldw); writes BT'
// [col][2K]: seg0=hi, seg1=lo.
__global__ __launch_bounds__(256) void prep_all(const float* __restrict__ w1,
                                                const float* __restrict__ w2,
                                                const float* __restrict__ w0,
                                                const float* __restrict__ wv,
                                                _Float16* __restrict__ W){
  const int PER_L = 475136;                      // 147456+245760+49152+32768
  int idx = blockIdx.x*256 + threadIdx.x;
  if (idx >= 2*PER_L) return;
  int l = idx / PER_L;
  int r = idx - l*PER_L;
  const float RS384 = 0.051031036307982884f;     // 1/sqrt(384)
  _Float16* WL = W + (size_t)l*950272;
  const float* src; _Float16* dst; int K, ldw, col, k; float scale;
  if (r < 147456){                               // w1: 384x384
    src = w1 + (size_t)l*147456; dst = WL;            K = 384; ldw = 384; scale = RS384;
    col = r / 384; k = r - col*384;
  } else if (r < 393216){                        // w2: 384x768, first 640 cols
    r -= 147456;
    src = w2 + (size_t)l*294912; dst = WL + 294912;   K = 384; ldw = 768; scale = RS384;
    col = r / 384; k = r - col*384;
  } else if (r < 442368){                        // w0: 384x128
    r -= 393216;
    src = w0 + (size_t)l*49152;  dst = WL + 786432;   K = 384; ldw = 128; scale = RS384;
    col = r / 384; k = r - col*384;
  } else {                                       // wv: 256x128
    r -= 442368;
    src = wv + (size_t)l*32768;  dst = WL + 884736;   K = 256; ldw = 128; scale = 0.0625f;
    col = r / 256; k = r - col*256;
  }
  float v = src[(size_t)k*ldw + col] * scale;
  _Float16 hi = (_Float16)v;
  _Float16 lo = (_Float16)(v - (float)hi);
  size_t b = (size_t)col*2*K + k;
  dst[b]     = hi;
  dst[b + K] = lo;
}

// ---------------------------- E0: unpack x + build sc' ---------------------
__global__ __launch_bounds__(256) void e0_fused(const float* __restrict__ x,
                                                float* __restrict__ S,
                                                float* __restrict__ V,
                                                _Float16* __restrict__ A1,
                                                int row0){
  __shared__ alignas(16) float lx[4][512];
  const int n0 = blockIdx.x*4;
  const int tid = threadIdx.x;
  const float4* xs = (const float4*)(x + (size_t)(row0 + n0)*512);
  float4* ls = (float4*)(&lx[0][0]);
  ls[tid]       = xs[tid];
  ls[tid + 256] = xs[tid + 256];
  __syncthreads();
  const int w = tid >> 6, lane = tid & 63;
  const int n = n0 + w;
  const float* row = &lx[w][0];
  #pragma unroll
  for (int h = 0; h < 2; ++h){
    int ch = h*64 + lane;
    float s = row[ch];
    S[(size_t)n*128 + ch] = s;
    float vv = 0.f;
    #pragma unroll
    for (int d = 0; d < 3; ++d){
      float vd = row[128 + ch*3 + d];
      V[((size_t)n*3 + d)*128 + ch] = vd;
      vv += vd*vd;
    }
    float vals[3] = { s, s*s, vv * 0.5773502691896258f };   // 1/sqrt(3)
    #pragma unroll
    for (int q = 0; q < 3; ++q){
      size_t b = (size_t)n*768 + q*128 + ch;
      split_store(&A1[b], &A1[b + 384], vals[q]);
    }
  }
}

// ---------------------------- E3: residual + LN / final --------------------
__global__ __launch_bounds__(256) void e3_fin(float* __restrict__ S, float* __restrict__ V,
                                              const float* __restrict__ OS, const float* __restrict__ OV,
                                              const float* __restrict__ g0, const float* __restrict__ g1,
                                              float* __restrict__ out, _Float16* __restrict__ A1,
                                              int row0, int doln){
  int n = blockIdx.x*4 + (threadIdx.x >> 6);
  int lane = threadIdx.x & 63;
  size_t sb = (size_t)n*128;
  size_t vb = (size_t)n*384;
  float s0 = S[sb + lane]      + OS[sb + lane];
  float s1 = S[sb + 64 + lane] + OS[sb + 64 + lane];
  float v[6];
  #pragma unroll
  for (int k = 0; k < 6; ++k) v[k] = V[vb + k*64 + lane] + OV[vb + k*64 + lane];

  if (doln){
    float mu = wave_sum64(s0 + s1) * (1.0f/128.0f);
    float d0 = s0 - mu, d1 = s1 - mu;
    float var = wave_sum64(d0*d0 + d1*d1) * (1.0f/128.0f);
    float sd = sqrtf(var + 1e-6f);
    float vvsum = 0.f;
    #pragma unroll
    for (int k = 0; k < 6; ++k) vvsum += v[k]*v[k];
    float rms = sqrtf(wave_sum64(vvsum) * (1.0f/384.0f) + 1e-6f);
    float s0n = d0 / sd * g0[lane];
    float s1n = d1 / sd * g0[64 + lane];
    S[sb + lane]      = s0n;
    S[sb + 64 + lane] = s1n;
    float vn[6];
    #pragma unroll
    for (int k = 0; k < 6; ++k){
      int j = k*64 + lane;
      vn[k] = v[k] / rms * g1[j & 127];
      V[vb + j] = vn[k];
    }
    // emit A1 = sc' = [s, s^2, |v|^2/sqrt3] hi/lo for the next layer
    float vv_a = vn[0]*vn[0] + vn[2]*vn[2] + vn[4]*vn[4];   // ch = lane
    float vv_b = vn[1]*vn[1] + vn[3]*vn[3] + vn[5]*vn[5];   // ch = 64+lane
    float va[3] = { s0n, s0n*s0n, vv_a * 0.5773502691896258f };
    float vbv[3]= { s1n, s1n*s1n, vv_b * 0.5773502691896258f };
    #pragma unroll
    for (int q = 0; q < 3; ++q){
      size_t ba = (size_t)n*768 + q*128 + lane;
      split_store(&A1[ba], &A1[ba + 384], va[q]);
      size_t bb = ba + 64;
      split_store(&A1[bb], &A1[bb + 384], vbv[q]);
    }
  } else {
    size_t ob = (size_t)(row0 + n)*512;
    out[ob + lane]      = s0;
    out[ob + 64 + lane] = s1;
    #pragma unroll
    for (int k = 0; k < 6; ++k){
      int j = k*64 + lane;
      int d = j >> 7, ch = j & 127;
      out[ob + 128 + ch*3 + d] = v[k];
    }
  }
}

// ---------------------------- split-GEMM main loop (128x64 tile) -----------
// C[128 x 64] += A[128 x 2*kbase (hi|lo)] x BT[64 x 2*kbase (hi|lo)]^T
// = hi*hi + hi*lo + lo*hi, fused per 32-k chunk: one barrier round stages
// {A_hi 8K, A_lo 8K, B_hi 4K, B_lo 4K} = 24 KB/buf; 12 ds_read_b128 +
// 24 MFMA per wave per barrier.
// DEPTH-2 PREFETCH over 3 buffers: counted s_waitcnt vmcnt(6) + raw
// s_barrier -- chunk c's loads issued 2 phases before use. Per-wave wait
// BEFORE barrier => all waves' chunk-c data visible after it. stage(c+2)
// overwrites buf[(c+2)%3] whose readers drained lgkm before this barrier.
// sched_barrier(0) after the s_barrier pins the cross-wave LDS reads BELOW
// the barrier (raw s_barrier is not a compiler fence -- r9 race fix).
// LDS XOR-swizzle per 4KB region: phys = byte ^ (((byte>>7)&3)<<4); dest
// linear, SOURCE pre-swizzled, reads use slot = kg ^ ((r>>1)&3).
__device__ __forceinline__ void gemm_mainloop(const _Float16* __restrict__ A,
                                              const _Float16* __restrict__ BT,
                                              int lda, int kbase, int m0, int c0,
                                              _Float16 (&ls)[3][12288],
                                              floatx4 (&acc)[4][2]){
  const int nsc  = kbase >> 5;       // fused chunks (12 or 8)
  const int ldbt = 2*kbase;
  const int tid  = threadIdx.x;
  const int wave = tid >> 6, lane = tid & 63;
  const int wm = wave & 1, wn = wave >> 1;
  const int r = lane & 15, kg = lane >> 4;
  const int slot = kg ^ ((r >> 1) & 3);

  auto stage = [&](int c, int buf){
    const int ka = c << 5;
    char* lb = (char*)(&ls[buf][0]);
    #pragma unroll
    for (int p = 0; p < 2; ++p){                     // A hi, A lo: 8 KB each
      const int lbase = wave*1024 + p*4096;
      const int off = lbase + lane*16;
      const int row = off >> 6;
      const int bir = (off & 63) ^ (((off >> 7) & 3) << 4);  // pre-swizzled src
      const char* gah = (const char*)A + (((size_t)(m0 + row))*lda + ka)*2 + bir;
      stage16(gah, lb + lbase);                      // A_hi [0,8192)
      const char* gal = (const char*)A + (((size_t)(m0 + row))*lda + kbase + ka)*2 + bir;
      stage16(gal, lb + 8192 + lbase);               // A_lo [8192,16384)
    }
    {                                                // B hi, B lo: 4 KB each
      const int lbase = wave*1024;
      const int off = lbase + lane*16;
      const int row = off >> 6;
      const int bir = (off & 63) ^ (((off >> 7) & 3) << 4);
      const char* gbh = (const char*)BT + (((size_t)(c0 + row))*ldbt + ka)*2 + bir;
      stage16(gbh, lb + 16384 + lbase);              // B_hi [16384,20480)
      const char* gbl = (const char*)BT + (((size_t)(c0 + row))*ldbt + kbase + ka)*2 + bir;
      stage16(gbl, lb + 20480 + lbase);              // B_lo [20480,24576)
    }
  };

  stage(0, 0); stage(1, 1);                          // 12 loads/wave in flight
  for (int c = 0; c < nsc; ++c){
    // keep prior iteration's work above the wait
    __builtin_amdgcn_sched_barrier(0);
    // wait for chunk c's 6 per-wave loads; leave chunk c+1's 6 in flight
    if (c + 1 < nsc) asm volatile("s_waitcnt vmcnt(6)" ::: "memory");
    else             asm volatile("s_waitcnt vmcnt(0)" ::: "memory");
    __builtin_amdgcn_s_barrier();
    __builtin_amdgcn_sched_barrier(0);               // pin LDS reads below barrier
    if (c + 2 < nsc) stage(c + 2, (c + 2) % 3);
    const char* base = (const char*)&ls[c % 3][0];
    half8 ah[4], al[4], bh[2], bl[2];
    #pragma unroll
    for (int mt = 0; mt < 4; ++mt){
      const int ro = (wm*64 + mt*16 + r)*64 + slot*16;
      ah[mt] = *(const half8*)(base + ro);
      al[mt] = *(const half8*)(base + 8192 + ro);
    }
    #pragma unroll
    for (int nt = 0; nt < 2; ++nt){
      const int ro = (wn*32 + nt*16 + r)*64 + slot*16;
      bh[nt] = *(const half8*)(base + 16384 + ro);
      bl[nt] = *(const half8*)(base + 20480 + ro);
    }
    #pragma unroll
    for (int mt = 0; mt < 4; ++mt)
      #pragma unroll
      for (int nt = 0; nt < 2; ++nt)
        acc[mt][nt] = __builtin_amdgcn_mfma_f32_16x16x32_f16(ah[mt], bh[nt], acc[mt][nt], 0, 0, 0);
    #pragma unroll
    for (int mt = 0; mt < 4; ++mt)
      #pragma unroll
      for (int nt = 0; nt < 2; ++nt)
        acc[mt][nt] = __builtin_amdgcn_mfma_f32_16x16x32_f16(ah[mt], bl[nt], acc[mt][nt], 0, 0, 0);
    #pragma unroll
    for (int mt = 0; mt < 4; ++mt)
      #pragma unroll
      for (int nt = 0; nt < 2; ++nt)
        acc[mt][nt] = __builtin_amdgcn_mfma_f32_16x16x32_f16(al[mt], bh[nt], acc[mt][nt], 0, 0, 0);
  }
}

// MODE 1: silu + hi/lo split into OUT (=A2, lda 768, lo at +384).
// MODE 2: fused gating epilogue (G never materialized):
//   c0<384 : A1 <- (A1hi+A1lo)*g in place (patch RMW through LDS)
//   c0>=384: A4[(n*3+d)*512+mm] <- vec[n,mm,d]*g hi/lo
// MERGED phases: full 128-row patches; ALL 4 waves modify. Scratch XOR
// swizzle pc = cl ^ (kg<<4) matched by the movers' chunk XOR.
template<int MODE>
__global__ __launch_bounds__(256, 2) void gemm_split(const _Float16* __restrict__ A,
                                                     const _Float16* __restrict__ BT,
                                                     _Float16* __restrict__ OUT,
                                                     const float* __restrict__ S,
                                                     const float* __restrict__ V,
                                                     _Float16* __restrict__ A1g,
                                                     _Float16* __restrict__ A4,
                                                     int lda, int kbase, int nx, int ny){
  __shared__ alignas(16) _Float16 ls[3][12288];   // 72 KB
  int bx, by; remap_xcd(blockIdx.x, nx, ny, bx, by);
  const int c0 = bx << 6, m0 = by << 7;
  floatx4 acc[4][2];
  #pragma unroll
  for (int i = 0; i < 4; ++i)
    #pragma unroll
    for (int j = 0; j < 2; ++j) acc[i][j] = (floatx4){0.f, 0.f, 0.f, 0.f};

  gemm_mainloop(A, BT, lda, kbase, m0, c0, ls, acc);

  const int tid = threadIdx.x;
  const int wave = tid >> 6, lane = tid & 63;
  const int wm = wave & 1, wn = wave >> 1;
  const int r = lane & 15, kg = lane >> 4;
  char* scr = (char*)&ls[0][0];                   // epilogue scratch (<=32 KB)

  if (MODE == 1){
    __syncthreads();                              // k-loop reads done
    #pragma unroll
    for (int mt = 0; mt < 4; ++mt)
      #pragma unroll
      for (int nt = 0; nt < 2; ++nt)
        #pragma unroll
        for (int i = 0; i < 4; ++i){
          int rl = wm*64 + mt*16 + kg*4 + i;      // 0..127
          int cl = wn*32 + nt*16 + r;             // 0..63
          int pc = cl ^ (kg << 4);
          float g = acc[mt][nt][i];
          float hh = g / (1.0f + __expf(-g));     // silu
          *(unsigned int*)(scr + rl*256 + pc*4) = pack_split(hh);
        }
    __syncthreads();
    #pragma unroll 1
    for (int j = 0; j < 8; ++j){                  // 128 rows x 256 B = 32 KB
      int lin = j*256 + tid, rl = lin >> 4, seg = lin & 15;
      int cs = seg ^ (((rl >> 2) & 3) << 2);
      uint4 p = *(const uint4*)(scr + rl*256 + cs*16);
      uint2 hi, lo; unzip16(p, hi, lo);
      _Float16* rowp = OUT + (size_t)(m0 + rl)*768 + c0 + seg*4;
      *(uint2*)rowp         = hi;
      *(uint2*)(rowp + 384) = lo;
    }
  } else if (c0 < 384){
    // ---- sc-gate: RMW the A1 hi/lo 128x64 patch through LDS
    __syncthreads();
    #pragma unroll 1
    for (int j = 0; j < 4; ++j){                  // hi 16 KB + lo 16 KB
      int lin = j*256 + tid, rl = lin >> 3, seg = lin & 7;
      int cs = seg ^ (((rl >> 2) & 3) << 1);
      const _Float16* gp = A1g + (size_t)(m0 + rl)*768 + c0 + seg*8;
      *(float4*)(scr + rl*128 + cs*16)         = *(const float4*)gp;         // hi
      *(float4*)(scr + 16384 + rl*128 + cs*16) = *(const float4*)(gp + 384); // lo
    }
    __syncthreads();
    #pragma unroll
    for (int mt = 0; mt < 4; ++mt)
      #pragma unroll
      for (int nt = 0; nt < 2; ++nt)
        #pragma unroll
        for (int i = 0; i < 4; ++i){
          int rl = wm*64 + mt*16 + kg*4 + i;
          int cl = wn*32 + nt*16 + r;
          int pc = cl ^ (kg << 4);
          _Float16* phi = (_Float16*)scr + rl*64 + pc;
          _Float16* plo = (_Float16*)(scr + 16384) + rl*64 + pc;
          float sc = (float)*phi + (float)*plo;
          split_store(phi, plo, sc * acc[mt][nt][i]);
        }
    __syncthreads();
    #pragma unroll 1
    for (int j = 0; j < 4; ++j){
      int lin = j*256 + tid, rl = lin >> 3, seg = lin & 7;
      int cs = seg ^ (((rl >> 2) & 3) << 1);
      _Float16* gp = A1g + (size_t)(m0 + rl)*768 + c0 + seg*8;
      *(float4*)gp         = *(const float4*)(scr + rl*128 + cs*16);
      *(float4*)(gp + 384) = *(const float4*)(scr + 16384 + rl*128 + cs*16);
    }
  } else {
    // ---- vec-gate: c0 in {384,448,512,576}; mm panel = c0-384
    const int mm0 = c0 - 384;
    const int ch0 = mm0 & 127;
    if (mm0 >= 128){
      // fold sqrt2*S into acc once
      #pragma unroll
      for (int mt = 0; mt < 4; ++mt)
        #pragma unroll
        for (int nt = 0; nt < 2; ++nt)
          #pragma unroll
          for (int i = 0; i < 4; ++i){
            int row = m0 + wm*64 + mt*16 + kg*4 + i;
            int cl  = wn*32 + nt*16 + r;
            acc[mt][nt][i] *= 1.4142135623730951f * S[(size_t)row*128 + ch0 + cl];
          }
    }
    for (int d = 0; d < 3; ++d){
      __syncthreads();
      #pragma unroll 1
      for (int j = 0; j < 8; ++j){                // V patch: 128 rows x 256 B
        int lin = j*256 + tid, rl = lin >> 4, seg = lin & 15;
        int cs = seg ^ (((rl >> 2) & 3) << 2);
        *(float4*)(scr + rl*256 + cs*16) =
          *(const float4*)(V + ((size_t)(m0 + rl)*3 + d)*128 + ch0 + seg*4);
      }
      __syncthreads();
      #pragma unroll
      for (int mt = 0; mt < 4; ++mt)
        #pragma unroll
        for (int nt = 0; nt < 2; ++nt)
          #pragma unroll
          for (int i = 0; i < 4; ++i){
            int rl = wm*64 + mt*16 + kg*4 + i;
            int cl = wn*32 + nt*16 + r;
            int pc = cl ^ (kg << 4);
            float* pw = (float*)(scr + rl*256) + pc;
            *(unsigned int*)pw = pack_split(*pw * acc[mt][nt][i]);
          }
      __syncthreads();
      #pragma unroll 1
      for (int j = 0; j < 8; ++j){
        int lin = j*256 + tid, rl = lin >> 4, seg = lin & 15;
        int cs = seg ^ (((rl >> 2) & 3) << 2);
        uint4 p = *(const uint4*)(scr + rl*256 + cs*16);
        uint2 hi, lo; unzip16(p, hi, lo);
        _Float16* rowp = A4 + ((size_t)(m0 + rl)*3 + d)*512 + mm0 + seg*4;
        *(uint2*)rowp         = hi;
        *(uint2*)(rowp + 256) = lo;
      }
    }
  }
}

// GEMM0 (A1 x W0 -> OS, 2*ny0 blocks) and GEMMV (A4 x WV -> OV, 2*ny1 blocks)
// in one dispatch; each part XCD-remapped; plain f32 coalesced store.
__global__ __launch_bounds__(256, 2) void gemm_pair(const _Float16* __restrict__ Aa,
                                                    const _Float16* __restrict__ Ba,
                                                    float* __restrict__ Ca, int ny0,
                                                    const _Float16* __restrict__ Ab,
                                                    const _Float16* __restrict__ Bb,
                                                    float* __restrict__ Cb, int ny1){
  __shared__ alignas(16) _Float16 ls[3][12288];
  const _Float16 *A, *BT; float* C; int lda, kbase, bx, by;
  const int id = blockIdx.x;
  if (id < 2*ny0){
    remap_xcd(id, 2, ny0, bx, by);
    A = Aa; BT = Ba; C = Ca; lda = 768; kbase = 384;
  } else {
    remap_xcd(id - 2*ny0, 2, ny1, bx, by);
    A = Ab; BT = Bb; C = Cb; lda = 512; kbase = 256;
  }
  const int c0 = bx << 6, m0 = by << 7;
  floatx4 acc[4][2];
  #pragma unroll
  for (int i = 0; i < 4; ++i)
    #pragma unroll
    for (int j = 0; j < 2; ++j) acc[i][j] = (floatx4){0.f, 0.f, 0.f, 0.f};

  gemm_mainloop(A, BT, lda, kbase, m0, c0, ls, acc);

  const int wave = threadIdx.x >> 6, lane = threadIdx.x & 63;
  const int wm = wave & 1, wn = wave >> 1;
  const int r = lane & 15, kg = lane >> 4;
  #pragma unroll
  for (int mt = 0; mt < 4; ++mt)
    #pragma unroll
    for (int nt = 0; nt < 2; ++nt)
      #pragma unroll
      for (int i = 0; i < 4; ++i){
        const int row = m0 + wm*64 + mt*16 + kg*4 + i;
        const int col = c0 + wn*32 + nt*16 + r;
        C[(size_t)row*128 + col] = acc[mt][nt][i];
      }
}

// ---------------------------- host launcher --------------------------------

extern "C" void kernel_launch(void* const* d_in, const int* in_sizes, int n_in,
                              void* d_out, int out_size, void* d_ws, size_t ws_size,
                              hipStream_t stream){
  const float* x  = (const float*)d_in[0];
  const float* w1 = (const float*)d_in[1];
  const float* w2 = (const float*)d_in[2];
  const float* w0 = (const float*)d_in[3];
  const float* wv = (const float*)d_in[4];
  const float* g0 = (const float*)d_in[5];
  const float* g1 = (const float*)d_in[6];
  float* out = (float*)d_out;
  const int N = in_sizes[0] / 512;                 // 16384

  // split-weight arena: per layer 950,272 halves ([col][2K] hi|lo)
  const size_t HL = 950272;
  _Float16* W = (_Float16*)d_ws;
  const size_t wbytes = 2*HL*2;                    // 3,801,088 B

  // pick N-chunking that fits ws (activations cost 10240 B/row)
  int cnum = 128;
  for (int cc = 1; cc <= 128; cc <<= 1){
    size_t need = wbytes + (size_t)(N/cc)*10240;
    if (need <= ws_size){ cnum = cc; break; }
  }
  const int R = N / cnum;                          // multiple of 128
  const int ny = R / 128;

  char* p = (char*)d_ws + wbytes;
  float*    Sst = (float*)p;     p += (size_t)R*512;
  float*    Vst = (float*)p;     p += (size_t)R*1536;
  _Float16* A1  = (_Float16*)p;  p += (size_t)R*1536;   // sc' then gated sc'
  _Float16* A2  = (_Float16*)p;  p += (size_t)R*1536;   // h'
  _Float16* A4  = (_Float16*)p;  p += (size_t)R*3072;   // gated vec' (3R x 512)
  float*    OS  = (float*)p;     p += (size_t)R*512;
  float*    OV  = (float*)p;     p += (size_t)R*1536;

  // weight prep (runs every call; ws is re-poisoned before each timed launch)
  prep_all<<<cdiv_h(2*475136,256),256,0,stream>>>(w1, w2, w0, wv, W);

  for (int chk = 0; chk < cnum; ++chk){
    const int row0 = chk*R;
    e0_fused<<<R/4,256,0,stream>>>(x, Sst, Vst, A1, row0);
    for (int l = 0; l < 2; ++l){
      _Float16* W1p = W + (size_t)l*HL;
      _Float16* W2p = W1p + 294912;
      _Float16* W0p = W1p + 786432;
      _Float16* WVp = W1p + 884736;
      gemm_split<1><<<6*ny,256,0,stream>>>(A1, W1p, A2,
          nullptr, nullptr, nullptr, nullptr, 768, 384, 6, ny);
      gemm_split<2><<<10*ny,256,0,stream>>>(A2, W2p, nullptr,
          Sst, Vst, A1, A4, 768, 384, 10, ny);
      gemm_pair<<<8*ny,256,0,stream>>>(A1, W0p, OS, ny, A4, WVp, OV, 3*ny);
      e3_fin<<<R/4,256,0,stream>>>(Sst, Vst, OS, OV, g0, g1, out, A1, row0, (l == 0) ? 1 : 0);
    }
  }
}

// Round 11
// 346.345 us; speedup vs baseline: 1.0676x; 1.0676x over previous
//
#include <hip/hip_runtime.h>

// ---------------------------------------------------------------------------
// SelfInteraction: 2 layers of (tensor-square -> invariant-gated MLP -> equiv
// linear) + residual + eq-layernorm, N=16384 rows, C=128, all fp32 I/O.
// fp16 hi/lo split-precision MFMA GEMMs (22-bit effective mantissa).
// Revision r11 = per-kernel best-of (r8 x r10 hybrid):
//   * r10 post-mortem: depth-2 helped GEMM2 (66.3->62.3us, grid 5 blocks/CU
//     pipelines across residency rounds) but its 72KB/2-blocks-CU footprint
//     broke GEMM1 (grid=3/CU: 1 round -> 2 rounds, +50%) and gemm_pair
//     (4/CU). Occupancy-granularity is per-grid.
//   * Hybrid: GEMM2 keeps the depth-2 counted-vmcnt loop (3x24KB, vmcnt(6),
//     sched_barrier-hardened). GEMM1 + gemm_pair revert to r8's depth-1
//     2-buffer __syncthreads loop (48KB, 3 blocks/CU).
//   * Everything else unchanged: fused 3-pass chunks (24 MFMA/wave/barrier),
//     merged epilogue phases, [col][2K] weights, XCD remap, both-sides
//     swizzles, LDS-staged coalesced epilogue I/O.
// ---------------------------------------------------------------------------

typedef _Float16 half8 __attribute__((ext_vector_type(8)));
typedef float floatx4 __attribute__((ext_vector_type(4)));

static inline int cdiv_h(int a, int b){ return (a + b - 1) / b; }

// ---------------------------- device helpers -------------------------------

__device__ __forceinline__ void stage16(const char* gaddr, char* lds_base){
  // dest = wave-uniform base + lane*16 (measured semantics, learn_hip m104/m108)
  __builtin_amdgcn_global_load_lds((const __attribute__((address_space(1))) unsigned int*)gaddr,
                                   (__attribute__((address_space(3))) unsigned int*)lds_base,
                                   16, 0, 0);
}

__device__ __forceinline__ float wave_sum64(float x){
  #pragma unroll
  for (int m = 32; m; m >>= 1) x += __shfl_xor(x, m, 64);
  return x;
}

__device__ __forceinline__ void split_store(_Float16* p0, _Float16* p1, float v){
  _Float16 hi = (_Float16)v;
  *p0 = hi;
  *p1 = (_Float16)(v - (float)hi);
}

// pack (hi,lo) split of v into one uint (hi in low 16 bits)
__device__ __forceinline__ unsigned int pack_split(float v){
  union { _Float16 h[2]; unsigned int u; } pk;
  _Float16 hi = (_Float16)v;
  pk.h[0] = hi;
  pk.h[1] = (_Float16)(v - (float)hi);
  return pk.u;
}

// 4 packed (hi,lo) uints -> (hi0..3, lo0..3) as two uint2
__device__ __forceinline__ void unzip16(uint4 p, uint2& hi, uint2& lo){
  hi.x = (p.x & 0xffffu) | (p.y << 16);
  hi.y = (p.z & 0xffffu) | (p.w << 16);
  lo.x = (p.x >> 16) | (p.y & 0xffff0000u);
  lo.y = (p.z >> 16) | (p.w & 0xffff0000u);
}

// XCD-grouped remap: with round-robin dispatch (block i -> XCD i&7), all nx
// col-panel blocks of row panel y get the same (i&7) -> same XCD L2.
// Bijective for ny%8==0; identity fallback otherwise (correctness-safe).
__device__ __forceinline__ void remap_xcd(int id, int nx, int ny, int& x, int& y){
  if (ny & 7){ x = id % nx; y = id / nx; return; }
  int xcd = id & 7, q = id >> 3, t = q / nx;
  x = q - t*nx; y = xcd + (t << 3);
}

// ---------------------------- weight prep ----------------------------------
// All 8 weight-prep jobs in one launch. w row-major (K, ldw); writes BT'
// [col][2K]: seg0=hi, seg1=lo.
__global__ __launch_bounds__(256) void prep_all(const float* __restrict__ w1,
                                                const float* __restrict__ w2,
                                                const float* __restrict__ w0,
                                                const float* __restrict__ wv,
                                                _Float16* __restrict__ W){
  const int PER_L = 475136;                      // 147456+245760+49152+32768
  int idx = blockIdx.x*256 + threadIdx.x;
  if (idx >= 2*PER_L) return;
  int l = idx / PER_L;
  int r = idx - l*PER_L;
  const float RS384 = 0.051031036307982884f;     // 1/sqrt(384)
  _Float16* WL = W + (size_t)l*950272;
  const float* src; _Float16* dst; int K, ldw, col, k; float scale;
  if (r < 147456){                               // w1: 384x384
    src = w1 + (size_t)l*147456; dst = WL;            K = 384; ldw = 384; scale = RS384;
    col = r / 384; k = r - col*384;
  } else if (r < 393216){                        // w2: 384x768, first 640 cols
    r -= 147456;
    src = w2 + (size_t)l*294912; dst = WL + 294912;   K = 384; ldw = 768; scale = RS384;
    col = r / 384; k = r - col*384;
  } else if (r < 442368){                        // w0: 384x128
    r -= 393216;
    src = w0 + (size_t)l*49152;  dst = WL + 786432;   K = 384; ldw = 128; scale = RS384;
    col = r / 384; k = r - col*384;
  } else {                                       // wv: 256x128
    r -= 442368;
    src = wv + (size_t)l*32768;  dst = WL + 884736;   K = 256; ldw = 128; scale = 0.0625f;
    col = r / 256; k = r - col*256;
  }
  float v = src[(size_t)k*ldw + col] * scale;
  _Float16 hi = (_Float16)v;
  _Float16 lo = (_Float16)(v - (float)hi);
  size_t b = (size_t)col*2*K + k;
  dst[b]     = hi;
  dst[b + K] = lo;
}

// ---------------------------- E0: unpack x + build sc' ---------------------
__global__ __launch_bounds__(256) void e0_fused(const float* __restrict__ x,
                                                float* __restrict__ S,
                                                float* __restrict__ V,
                                                _Float16* __restrict__ A1,
                                                int row0){
  __shared__ alignas(16) float lx[4][512];
  const int n0 = blockIdx.x*4;
  const int tid = threadIdx.x;
  const float4* xs = (const float4*)(x + (size_t)(row0 + n0)*512);
  float4* ls = (float4*)(&lx[0][0]);
  ls[tid]       = xs[tid];
  ls[tid + 256] = xs[tid + 256];
  __syncthreads();
  const int w = tid >> 6, lane = tid & 63;
  const int n = n0 + w;
  const float* row = &lx[w][0];
  #pragma unroll
  for (int h = 0; h < 2; ++h){
    int ch = h*64 + lane;
    float s = row[ch];
    S[(size_t)n*128 + ch] = s;
    float vv = 0.f;
    #pragma unroll
    for (int d = 0; d < 3; ++d){
      float vd = row[128 + ch*3 + d];
      V[((size_t)n*3 + d)*128 + ch] = vd;
      vv += vd*vd;
    }
    float vals[3] = { s, s*s, vv * 0.5773502691896258f };   // 1/sqrt(3)
    #pragma unroll
    for (int q = 0; q < 3; ++q){
      size_t b = (size_t)n*768 + q*128 + ch;
      split_store(&A1[b], &A1[b + 384], vals[q]);
    }
  }
}

// ---------------------------- E3: residual + LN / final --------------------
__global__ __launch_bounds__(256) void e3_fin(float* __restrict__ S, float* __restrict__ V,
                                              const float* __restrict__ OS, const float* __restrict__ OV,
                                              const float* __restrict__ g0, const float* __restrict__ g1,
                                              float* __restrict__ out, _Float16* __restrict__ A1,
                                              int row0, int doln){
  int n = blockIdx.x*4 + (threadIdx.x >> 6);
  int lane = threadIdx.x & 63;
  size_t sb = (size_t)n*128;
  size_t vb = (size_t)n*384;
  float s0 = S[sb + lane]      + OS[sb + lane];
  float s1 = S[sb + 64 + lane] + OS[sb + 64 + lane];
  float v[6];
  #pragma unroll
  for (int k = 0; k < 6; ++k) v[k] = V[vb + k*64 + lane] + OV[vb + k*64 + lane];

  if (doln){
    float mu = wave_sum64(s0 + s1) * (1.0f/128.0f);
    float d0 = s0 - mu, d1 = s1 - mu;
    float var = wave_sum64(d0*d0 + d1*d1) * (1.0f/128.0f);
    float sd = sqrtf(var + 1e-6f);
    float vvsum = 0.f;
    #pragma unroll
    for (int k = 0; k < 6; ++k) vvsum += v[k]*v[k];
    float rms = sqrtf(wave_sum64(vvsum) * (1.0f/384.0f) + 1e-6f);
    float s0n = d0 / sd * g0[lane];
    float s1n = d1 / sd * g0[64 + lane];
    S[sb + lane]      = s0n;
    S[sb + 64 + lane] = s1n;
    float vn[6];
    #pragma unroll
    for (int k = 0; k < 6; ++k){
      int j = k*64 + lane;
      vn[k] = v[k] / rms * g1[j & 127];
      V[vb + j] = vn[k];
    }
    // emit A1 = sc' = [s, s^2, |v|^2/sqrt3] hi/lo for the next layer
    float vv_a = vn[0]*vn[0] + vn[2]*vn[2] + vn[4]*vn[4];   // ch = lane
    float vv_b = vn[1]*vn[1] + vn[3]*vn[3] + vn[5]*vn[5];   // ch = 64+lane
    float va[3] = { s0n, s0n*s0n, vv_a * 0.5773502691896258f };
    float vbv[3]= { s1n, s1n*s1n, vv_b * 0.5773502691896258f };
    #pragma unroll
    for (int q = 0; q < 3; ++q){
      size_t ba = (size_t)n*768 + q*128 + lane;
      split_store(&A1[ba], &A1[ba + 384], va[q]);
      size_t bb = ba + 64;
      split_store(&A1[bb], &A1[bb + 384], vbv[q]);
    }
  } else {
    size_t ob = (size_t)(row0 + n)*512;
    out[ob + lane]      = s0;
    out[ob + 64 + lane] = s1;
    #pragma unroll
    for (int k = 0; k < 6; ++k){
      int j = k*64 + lane;
      int d = j >> 7, ch = j & 127;
      out[ob + 128 + ch*3 + d] = v[k];
    }
  }
}

// ---------------------------- split-GEMM main loop (128x64 tile) -----------
// C[128 x 64] += A[128 x 2*kbase (hi|lo)] x BT[64 x 2*kbase (hi|lo)]^T
// = hi*hi + hi*lo + lo*hi, fused per 32-k chunk: one barrier round stages
// {A_hi 8K, A_lo 8K, B_hi 4K, B_lo 4K} = 24 KB/buf; 12 ds_read_b128 +
// 24 MFMA per wave per barrier.
// NBUF=2: depth-1, plain __syncthreads 2-buffer loop (r8; best for grids
//         at exact-residency granularity: 3-4 blocks/CU at 48 KB).
// NBUF=3: depth-2 prefetch, counted s_waitcnt vmcnt(6) + raw s_barrier
//         (r10; best for GEMM2's 5-blocks/CU grid). sched_barrier(0) after
//         the s_barrier pins cross-wave LDS reads below it (raw s_barrier
//         is not a compiler fence).
// LDS XOR-swizzle per 4KB region: phys = byte ^ (((byte>>7)&3)<<4); dest
// linear, SOURCE pre-swizzled, reads use slot = kg ^ ((r>>1)&3).
template<int NBUF>
__device__ __forceinline__ void gemm_mainloop(const _Float16* __restrict__ A,
                                              const _Float16* __restrict__ BT,
                                              int lda, int kbase, int m0, int c0,
                                              _Float16 (&ls)[NBUF][12288],
                                              floatx4 (&acc)[4][2]){
  const int nsc  = kbase >> 5;       // fused chunks (12 or 8)
  const int ldbt = 2*kbase;
  const int tid  = threadIdx.x;
  const int wave = tid >> 6, lane = tid & 63;
  const int wm = wave & 1, wn = wave >> 1;
  const int r = lane & 15, kg = lane >> 4;
  const int slot = kg ^ ((r >> 1) & 3);

  auto stage = [&](int c, int buf){
    const int ka = c << 5;
    char* lb = (char*)(&ls[buf][0]);
    #pragma unroll
    for (int p = 0; p < 2; ++p){                     // A hi, A lo: 8 KB each
      const int lbase = wave*1024 + p*4096;
      const int off = lbase + lane*16;
      const int row = off >> 6;
      const int bir = (off & 63) ^ (((off >> 7) & 3) << 4);  // pre-swizzled src
      const char* gah = (const char*)A + (((size_t)(m0 + row))*lda + ka)*2 + bir;
      stage16(gah, lb + lbase);                      // A_hi [0,8192)
      const char* gal = (const char*)A + (((size_t)(m0 + row))*lda + kbase + ka)*2 + bir;
      stage16(gal, lb + 8192 + lbase);               // A_lo [8192,16384)
    }
    {                                                // B hi, B lo: 4 KB each
      const int lbase = wave*1024;
      const int off = lbase + lane*16;
      const int row = off >> 6;
      const int bir = (off & 63) ^ (((off >> 7) & 3) << 4);
      const char* gbh = (const char*)BT + (((size_t)(c0 + row))*ldbt + ka)*2 + bir;
      stage16(gbh, lb + 16384 + lbase);              // B_hi [16384,20480)
      const char* gbl = (const char*)BT + (((size_t)(c0 + row))*ldbt + kbase + ka)*2 + bir;
      stage16(gbl, lb + 20480 + lbase);              // B_lo [20480,24576)
    }
  };

  auto compute = [&](const char* base){
    half8 ah[4], al[4], bh[2], bl[2];
    #pragma unroll
    for (int mt = 0; mt < 4; ++mt){
      const int ro = (wm*64 + mt*16 + r)*64 + slot*16;
      ah[mt] = *(const half8*)(base + ro);
      al[mt] = *(const half8*)(base + 8192 + ro);
    }
    #pragma unroll
    for (int nt = 0; nt < 2; ++nt){
      const int ro = (wn*32 + nt*16 + r)*64 + slot*16;
      bh[nt] = *(const half8*)(base + 16384 + ro);
      bl[nt] = *(const half8*)(base + 20480 + ro);
    }
    #pragma unroll
    for (int mt = 0; mt < 4; ++mt)
      #pragma unroll
      for (int nt = 0; nt < 2; ++nt)
        acc[mt][nt] = __builtin_amdgcn_mfma_f32_16x16x32_f16(ah[mt], bh[nt], acc[mt][nt], 0, 0, 0);
    #pragma unroll
    for (int mt = 0; mt < 4; ++mt)
      #pragma unroll
      for (int nt = 0; nt < 2; ++nt)
        acc[mt][nt] = __builtin_amdgcn_mfma_f32_16x16x32_f16(ah[mt], bl[nt], acc[mt][nt], 0, 0, 0);
    #pragma unroll
    for (int mt = 0; mt < 4; ++mt)
      #pragma unroll
      for (int nt = 0; nt < 2; ++nt)
        acc[mt][nt] = __builtin_amdgcn_mfma_f32_16x16x32_f16(al[mt], bh[nt], acc[mt][nt], 0, 0, 0);
  };

  if (NBUF == 2){
    // ---- depth-1 (r8): plain 2-buffer __syncthreads loop
    stage(0, 0);
    for (int c = 0; c < nsc; ++c){
      __syncthreads();                    // drains vmcnt -> buf[c&1] ready
      if (c + 1 < nsc) stage(c + 1, (c + 1) & 1);
      compute((const char*)&ls[c & 1][0]);
    }
  } else {
    // ---- depth-2 (r10): 3 buffers, counted vmcnt, raw barrier
    stage(0, 0); stage(1, 1);             // 12 loads/wave in flight
    for (int c = 0; c < nsc; ++c){
      __builtin_amdgcn_sched_barrier(0);  // keep prior work above the wait
      if (c + 1 < nsc) asm volatile("s_waitcnt vmcnt(6)" ::: "memory");
      else             asm volatile("s_waitcnt vmcnt(0)" ::: "memory");
      __builtin_amdgcn_s_barrier();
      __builtin_amdgcn_sched_barrier(0);  // pin LDS reads below barrier
      if (c + 2 < nsc) stage(c + 2, (c + 2) % 3);
      compute((const char*)&ls[c % 3][0]);
    }
  }
}

// MODE 1: silu + hi/lo split into OUT (=A2, lda 768, lo at +384). Depth-1.
// MODE 2: fused gating epilogue (G never materialized). Depth-2.
//   c0<384 : A1 <- (A1hi+A1lo)*g in place (patch RMW through LDS)
//   c0>=384: A4[(n*3+d)*512+mm] <- vec[n,mm,d]*g hi/lo
// MERGED phases: full 128-row patches; ALL 4 waves modify. Scratch XOR
// swizzle pc = cl ^ (kg<<4) matched by the movers' chunk XOR.
template<int MODE>
__global__ __launch_bounds__(256, (MODE == 2) ? 2 : 3)
void gemm_split(const _Float16* __restrict__ A,
                const _Float16* __restrict__ BT,
                _Float16* __restrict__ OUT,
                const float* __restrict__ S,
                const float* __restrict__ V,
                _Float16* __restrict__ A1g,
                _Float16* __restrict__ A4,
                int lda, int kbase, int nx, int ny){
  __shared__ alignas(16) _Float16 ls[(MODE == 2) ? 3 : 2][12288];  // 72/48 KB
  int bx, by; remap_xcd(blockIdx.x, nx, ny, bx, by);
  const int c0 = bx << 6, m0 = by << 7;
  floatx4 acc[4][2];
  #pragma unroll
  for (int i = 0; i < 4; ++i)
    #pragma unroll
    for (int j = 0; j < 2; ++j) acc[i][j] = (floatx4){0.f, 0.f, 0.f, 0.f};

  gemm_mainloop(A, BT, lda, kbase, m0, c0, ls, acc);

  const int tid = threadIdx.x;
  const int wave = tid >> 6, lane = tid & 63;
  const int wm = wave & 1, wn = wave >> 1;
  const int r = lane & 15, kg = lane >> 4;
  char* scr = (char*)&ls[0][0];                   // epilogue scratch (<=32 KB)

  if (MODE == 1){
    __syncthreads();                              // k-loop reads done
    #pragma unroll
    for (int mt = 0; mt < 4; ++mt)
      #pragma unroll
      for (int nt = 0; nt < 2; ++nt)
        #pragma unroll
        for (int i = 0; i < 4; ++i){
          int rl = wm*64 + mt*16 + kg*4 + i;      // 0..127
          int cl = wn*32 + nt*16 + r;             // 0..63
          int pc = cl ^ (kg << 4);
          float g = acc[mt][nt][i];
          float hh = g / (1.0f + __expf(-g));     // silu
          *(unsigned int*)(scr + rl*256 + pc*4) = pack_split(hh);
        }
    __syncthreads();
    #pragma unroll 1
    for (int j = 0; j < 8; ++j){                  // 128 rows x 256 B = 32 KB
      int lin = j*256 + tid, rl = lin >> 4, seg = lin & 15;
      int cs = seg ^ (((rl >> 2) & 3) << 2);
      uint4 p = *(const uint4*)(scr + rl*256 + cs*16);
      uint2 hi, lo; unzip16(p, hi, lo);
      _Float16* rowp = OUT + (size_t)(m0 + rl)*768 + c0 + seg*4;
      *(uint2*)rowp         = hi;
      *(uint2*)(rowp + 384) = lo;
    }
  } else if (c0 < 384){
    // ---- sc-gate: RMW the A1 hi/lo 128x64 patch through LDS
    __syncthreads();
    #pragma unroll 1
    for (int j = 0; j < 4; ++j){                  // hi 16 KB + lo 16 KB
      int lin = j*256 + tid, rl = lin >> 3, seg = lin & 7;
      int cs = seg ^ (((rl >> 2) & 3) << 1);
      const _Float16* gp = A1g + (size_t)(m0 + rl)*768 + c0 + seg*8;
      *(float4*)(scr + rl*128 + cs*16)         = *(const float4*)gp;         // hi
      *(float4*)(scr + 16384 + rl*128 + cs*16) = *(const float4*)(gp + 384); // lo
    }
    __syncthreads();
    #pragma unroll
    for (int mt = 0; mt < 4; ++mt)
      #pragma unroll
      for (int nt = 0; nt < 2; ++nt)
        #pragma unroll
        for (int i = 0; i < 4; ++i){
          int rl = wm*64 + mt*16 + kg*4 + i;
          int cl = wn*32 + nt*16 + r;
          int pc = cl ^ (kg << 4);
          _Float16* phi = (_Float16*)scr + rl*64 + pc;
          _Float16* plo = (_Float16*)(scr + 16384) + rl*64 + pc;
          float sc = (float)*phi + (float)*plo;
          split_store(phi, plo, sc * acc[mt][nt][i]);
        }
    __syncthreads();
    #pragma unroll 1
    for (int j = 0; j < 4; ++j){
      int lin = j*256 + tid, rl = lin >> 3, seg = lin & 7;
      int cs = seg ^ (((rl >> 2) & 3) << 1);
      _Float16* gp = A1g + (size_t)(m0 + rl)*768 + c0 + seg*8;
      *(float4*)gp         = *(const float4*)(scr + rl*128 + cs*16);
      *(float4*)(gp + 384) = *(const float4*)(scr + 16384 + rl*128 + cs*16);
    }
  } else {
    // ---- vec-gate: c0 in {384,448,512,576}; mm panel = c0-384
    const int mm0 = c0 - 384;
    const int ch0 = mm0 & 127;
    if (mm0 >= 128){
      // fold sqrt2*S into acc once
      #pragma unroll
      for (int mt = 0; mt < 4; ++mt)
        #pragma unroll
        for (int nt = 0; nt < 2; ++nt)
          #pragma unroll
          for (int i = 0; i < 4; ++i){
            int row = m0 + wm*64 + mt*16 + kg*4 + i;
            int cl  = wn*32 + nt*16 + r;
            acc[mt][nt][i] *= 1.4142135623730951f * S[(size_t)row*128 + ch0 + cl];
          }
    }
    for (int d = 0; d < 3; ++d){
      __syncthreads();
      #pragma unroll 1
      for (int j = 0; j < 8; ++j){                // V patch: 128 rows x 256 B
        int lin = j*256 + tid, rl = lin >> 4, seg = lin & 15;
        int cs = seg ^ (((rl >> 2) & 3) << 2);
        *(float4*)(scr + rl*256 + cs*16) =
          *(const float4*)(V + ((size_t)(m0 + rl)*3 + d)*128 + ch0 + seg*4);
      }
      __syncthreads();
      #pragma unroll
      for (int mt = 0; mt < 4; ++mt)
        #pragma unroll
        for (int nt = 0; nt < 2; ++nt)
          #pragma unroll
          for (int i = 0; i < 4; ++i){
            int rl = wm*64 + mt*16 + kg*4 + i;
            int cl = wn*32 + nt*16 + r;
            int pc = cl ^ (kg << 4);
            float* pw = (float*)(scr + rl*256) + pc;
            *(unsigned int*)pw = pack_split(*pw * acc[mt][nt][i]);
          }
      __syncthreads();
      #pragma unroll 1
      for (int j = 0; j < 8; ++j){
        int lin = j*256 + tid, rl = lin >> 4, seg = lin & 15;
        int cs = seg ^ (((rl >> 2) & 3) << 2);
        uint4 p = *(const uint4*)(scr + rl*256 + cs*16);
        uint2 hi, lo; unzip16(p, hi, lo);
        _Float16* rowp = A4 + ((size_t)(m0 + rl)*3 + d)*512 + mm0 + seg*4;
        *(uint2*)rowp         = hi;
        *(uint2*)(rowp + 256) = lo;
      }
    }
  }
}

// GEMM0 (A1 x W0 -> OS, 2*ny0 blocks) and GEMMV (A4 x WV -> OV, 2*ny1 blocks)
// in one dispatch; each part XCD-remapped; plain f32 coalesced store.
// Depth-1 (48 KB, 3 blocks/CU) -- its grid is 4/CU, residency-granular.
__global__ __launch_bounds__(256, 3) void gemm_pair(const _Float16* __restrict__ Aa,
                                                    const _Float16* __restrict__ Ba,
                                                    float* __restrict__ Ca, int ny0,
                                                    const _Float16* __restrict__ Ab,
                                                    const _Float16* __restrict__ Bb,
                                                    float* __restrict__ Cb, int ny1){
  __shared__ alignas(16) _Float16 ls[2][12288];
  const _Float16 *A, *BT; float* C; int lda, kbase, bx, by;
  const int id = blockIdx.x;
  if (id < 2*ny0){
    remap_xcd(id, 2, ny0, bx, by);
    A = Aa; BT = Ba; C = Ca; lda = 768; kbase = 384;
  } else {
    remap_xcd(id - 2*ny0, 2, ny1, bx, by);
    A = Ab; BT = Bb; C = Cb; lda = 512; kbase = 256;
  }
  const int c0 = bx << 6, m0 = by << 7;
  floatx4 acc[4][2];
  #pragma unroll
  for (int i = 0; i < 4; ++i)
    #pragma unroll
    for (int j = 0; j < 2; ++j) acc[i][j] = (floatx4){0.f, 0.f, 0.f, 0.f};

  gemm_mainloop(A, BT, lda, kbase, m0, c0, ls, acc);

  const int wave = threadIdx.x >> 6, lane = threadIdx.x & 63;
  const int wm = wave & 1, wn = wave >> 1;
  const int r = lane & 15, kg = lane >> 4;
  #pragma unroll
  for (int mt = 0; mt < 4; ++mt)
    #pragma unroll
    for (int nt = 0; nt < 2; ++nt)
      #pragma unroll
      for (int i = 0; i < 4; ++i){
        const int row = m0 + wm*64 + mt*16 + kg*4 + i;
        const int col = c0 + wn*32 + nt*16 + r;
        C[(size_t)row*128 + col] = acc[mt][nt][i];
      }
}

// ---------------------------- host launcher --------------------------------

extern "C" void kernel_launch(void* const* d_in, const int* in_sizes, int n_in,
                              void* d_out, int out_size, void* d_ws, size_t ws_size,
                              hipStream_t stream){
  const float* x  = (const float*)d_in[0];
  const float* w1 = (const float*)d_in[1];
  const float* w2 = (const float*)d_in[2];
  const float* w0 = (const float*)d_in[3];
  const float* wv = (const float*)d_in[4];
  const float* g0 = (const float*)d_in[5];
  const float* g1 = (const float*)d_in[6];
  float* out = (float*)d_out;
  const int N = in_sizes[0] / 512;                 // 16384

  // split-weight arena: per layer 950,272 halves ([col][2K] hi|lo)
  const size_t HL = 950272;
  _Float16* W = (_Float16*)d_ws;
  const size_t wbytes = 2*HL*2;                    // 3,801,088 B

  // pick N-chunking that fits ws (activations cost 10240 B/row)
  int cnum = 128;
  for (int cc = 1; cc <= 128; cc <<= 1){
    size_t need = wbytes + (size_t)(N/cc)*10240;
    if (need <= ws_size){ cnum = cc; break; }
  }
  const int R = N / cnum;                          // multiple of 128
  const int ny = R / 128;

  char* p = (char*)d_ws + wbytes;
  float*    Sst = (float*)p;     p += (size_t)R*512;
  float*    Vst = (float*)p;     p += (size_t)R*1536;
  _Float16* A1  = (_Float16*)p;  p += (size_t)R*1536;   // sc' then gated sc'
  _Float16* A2  = (_Float16*)p;  p += (size_t)R*1536;   // h'
  _Float16* A4  = (_Float16*)p;  p += (size_t)R*3072;   // gated vec' (3R x 512)
  float*    OS  = (float*)p;     p += (size_t)R*512;
  float*    OV  = (float*)p;     p += (size_t)R*1536;

  // weight prep (runs every call; ws is re-poisoned before each timed launch)
  prep_all<<<cdiv_h(2*475136,256),256,0,stream>>>(w1, w2, w0, wv, W);

  for (int chk = 0; chk < cnum; ++chk){
    const int row0 = chk*R;
    e0_fused<<<R/4,256,0,stream>>>(x, Sst, Vst, A1, row0);
    for (int l = 0; l < 2; ++l){
      _Float16* W1p = W + (size_t)l*HL;
      _Float16* W2p = W1p + 294912;
      _Float16* W0p = W1p + 786432;
      _Float16* WVp = W1p + 884736;
      gemm_split<1><<<6*ny,256,0,stream>>>(A1, W1p, A2,
          nullptr, nullptr, nullptr, nullptr, 768, 384, 6, ny);
      gemm_split<2><<<10*ny,256,0,stream>>>(A2, W2p, nullptr,
          Sst, Vst, A1, A4, 768, 384, 10, ny);
      gemm_pair<<<8*ny,256,0,stream>>>(A1, W0p, OS, ny, A4, WVp, OV, 3*ny);
      e3_fin<<<R/4,256,0,stream>>>(Sst, Vst, OS, OV, g0, g1, out, A1, row0, (l == 0) ? 1 : 0);
    }
  }
}